// Round 9
// baseline (15406.863 us; speedup 1.0000x reference)
//
#include <hip/hip_runtime.h>
#include <hip/hip_bf16.h>
#include <math.h>

#define VOCAB 32000
#define TSEQ 1024
#define DMODEL 1024
#define NLAYERS 6
#define NHEADS 16
#define DFF 4096
#define DKH 64
#define BATCH 2
#define MROWS (BATCH * TSEQ)   // 2048
#define LN_EPS 1e-6f

// ---------------- embedding + positional encoding ----------------
__global__ void embed_kernel(const int* __restrict__ idx,
                             const float* __restrict__ emb,
                             float* __restrict__ x) {
    int i = blockIdx.x * blockDim.x + threadIdx.x;
    if (i >= MROWS * DMODEL) return;
    int row = i / DMODEL;      // b*T + t
    int d = i - row * DMODEL;
    int t = row % TSEQ;
    int tok = idx[row];
    float e = emb[(size_t)tok * DMODEL + d] * 32.0f;  // sqrt(1024)
    float freq = expf(-(float)(d & ~1) * (9.210340371976184f / (float)DMODEL));
    float ang = (float)t * freq;
    float pe = (d & 1) ? cosf(ang) : sinf(ang);
    x[i] = e + pe;
}

// ---------------- layernorm (ddof=1, denom = std + eps) ----------------
__global__ void __launch_bounds__(256) ln_kernel(const float* __restrict__ x,
                                                 const float* __restrict__ a,
                                                 const float* __restrict__ b,
                                                 float* __restrict__ y) {
    __shared__ float red[8];
    int row = blockIdx.x;
    int tid = threadIdx.x;
    float4 v = ((const float4*)(x + (size_t)row * DMODEL))[tid];
    float s = v.x + v.y + v.z + v.w;
    #pragma unroll
    for (int off = 32; off; off >>= 1) s += __shfl_xor(s, off, 64);
    if ((tid & 63) == 0) red[tid >> 6] = s;
    __syncthreads();
    float mean = (red[0] + red[1] + red[2] + red[3]) * (1.0f / DMODEL);
    float dx = v.x - mean, dy = v.y - mean, dz = v.z - mean, dw = v.w - mean;
    float ss = dx * dx + dy * dy + dz * dz + dw * dw;
    #pragma unroll
    for (int off = 32; off; off >>= 1) ss += __shfl_xor(ss, off, 64);
    if ((tid & 63) == 0) red[4 + (tid >> 6)] = ss;
    __syncthreads();
    float var = (red[4] + red[5] + red[6] + red[7]) * (1.0f / (DMODEL - 1));
    float inv = 1.0f / (sqrtf(var) + LN_EPS);
    const float4 a4 = ((const float4*)a)[tid];
    const float4 b4 = ((const float4*)b)[tid];
    float4 o;
    o.x = a4.x * dx * inv + b4.x;
    o.y = a4.y * dy * inv + b4.y;
    o.z = a4.z * dz * inv + b4.z;
    o.w = a4.w * dw * inv + b4.w;
    ((float4*)(y + (size_t)row * DMODEL))[tid] = o;
}

// ---------------- GEMM: C[M,N] = A[M,K] @ B[K,N] + epilogue (all f32) ----------------
#define BM 64
#define BN 64
#define BK 16

template<bool BIAS, bool RELU, bool RES>
__global__ void __launch_bounds__(256) gemm_kernel(
    const float* __restrict__ A, const float* __restrict__ Bw,
    const float* __restrict__ bias, const float* res,
    float* outp, int N, int K)
{
    __shared__ float As[BK][BM];
    __shared__ float Bs[BK][BN];
    const int bm = blockIdx.y * BM;
    const int bn = blockIdx.x * BN;
    const int tid = threadIdx.x;
    const int tr = (tid >> 4) << 2;   // output row base within tile
    const int tc = (tid & 15) << 2;   // output col base within tile
    const int am = tid >> 2;          // A-load row 0..63
    const int ak = (tid & 3) << 2;    // A-load k 0,4,8,12
    const int bk = tid >> 4;          // B-load k 0..15
    const int bn4 = (tid & 15) << 2;  // B-load col 0..60

    float acc[4][4] = {};
    const float* Ap = A + (size_t)(bm + am) * K + ak;
    const float* Bp = Bw + (size_t)bk * N + bn + bn4;

    for (int k0 = 0; k0 < K; k0 += BK) {
        float4 av = *(const float4*)(Ap + k0);
        float4 bv = *(const float4*)(Bp + (size_t)k0 * N);
        As[ak + 0][am] = av.x;
        As[ak + 1][am] = av.y;
        As[ak + 2][am] = av.z;
        As[ak + 3][am] = av.w;
        *(float4*)&Bs[bk][bn4] = bv;
        __syncthreads();
        #pragma unroll
        for (int kk = 0; kk < BK; ++kk) {
            float4 a4 = *(const float4*)&As[kk][tr];
            float4 b4 = *(const float4*)&Bs[kk][tc];
            acc[0][0] += a4.x * b4.x; acc[0][1] += a4.x * b4.y; acc[0][2] += a4.x * b4.z; acc[0][3] += a4.x * b4.w;
            acc[1][0] += a4.y * b4.x; acc[1][1] += a4.y * b4.y; acc[1][2] += a4.y * b4.z; acc[1][3] += a4.y * b4.w;
            acc[2][0] += a4.z * b4.x; acc[2][1] += a4.z * b4.y; acc[2][2] += a4.z * b4.z; acc[2][3] += a4.z * b4.w;
            acc[3][0] += a4.w * b4.x; acc[3][1] += a4.w * b4.y; acc[3][2] += a4.w * b4.z; acc[3][3] += a4.w * b4.w;
        }
        __syncthreads();
    }

    float bias4[4] = {0.f, 0.f, 0.f, 0.f};
    if (BIAS) {
        #pragma unroll
        for (int j = 0; j < 4; ++j) bias4[j] = bias[bn + tc + j];
    }
    #pragma unroll
    for (int i = 0; i < 4; ++i) {
        int row = bm + tr + i;
        float r0 = acc[i][0], r1 = acc[i][1], r2 = acc[i][2], r3 = acc[i][3];
        if (BIAS) { r0 += bias4[0]; r1 += bias4[1]; r2 += bias4[2]; r3 += bias4[3]; }
        if (RELU) { r0 = fmaxf(r0, 0.f); r1 = fmaxf(r1, 0.f); r2 = fmaxf(r2, 0.f); r3 = fmaxf(r3, 0.f); }
        if (RES) {
            float4 rv = *(const float4*)(res + (size_t)row * N + bn + tc);
            r0 += rv.x; r1 += rv.y; r2 += rv.z; r3 += rv.w;
        }
        float4 o; o.x = r0; o.y = r1; o.z = r2; o.w = r3;
        *(float4*)(outp + (size_t)row * N + bn + tc) = o;
    }
}

// ---------------- attention: one wave per (b, h, q-row), online softmax ----------------
__global__ void __launch_bounds__(64) attn_kernel(const float* __restrict__ q,
                                                  const float* __restrict__ k,
                                                  const float* __restrict__ v,
                                                  float* __restrict__ o) {
    int lane = threadIdx.x;
    int qi = blockIdx.x;
    int h = blockIdx.y;
    int b = blockIdx.z;
    const size_t base = (size_t)b * TSEQ * DMODEL + h * DKH;
    float qd = q[base + (size_t)qi * DMODEL + lane];
    float m = -1e30f, l = 0.f, od = 0.f;
    for (int j = 0; j <= qi; ++j) {
        float kd = k[base + (size_t)j * DMODEL + lane];
        float s = qd * kd;
        #pragma unroll
        for (int off = 32; off; off >>= 1) s += __shfl_xor(s, off, 64);
        s *= 0.125f;  // 1/sqrt(64)
        float mn = fmaxf(m, s);
        float c = __expf(m - mn);
        float p = __expf(s - mn);
        float vd = v[base + (size_t)j * DMODEL + lane];
        l = l * c + p;
        od = od * c + p * vd;
        m = mn;
    }
    o[base + (size_t)qi * DMODEL + lane] = od / l;
}

// ---------------- host ----------------
extern "C" void kernel_launch(void* const* d_in, const int* in_sizes, int n_in,
                              void* d_out, int out_size, void* d_ws, size_t ws_size,
                              hipStream_t stream) {
    const int* idx = (const int*)d_in[0];
    const float* emb = (const float*)d_in[1];
    const float* Wq = (const float*)d_in[2];
    const float* Wk = (const float*)d_in[3];
    const float* Wv = (const float*)d_in[4];
    const float* Wo = (const float*)d_in[5];
    const float* ln1a = (const float*)d_in[6];
    const float* ln1b = (const float*)d_in[7];
    const float* ln2a = (const float*)d_in[8];
    const float* ln2b = (const float*)d_in[9];
    const float* W1 = (const float*)d_in[10];
    const float* b1 = (const float*)d_in[11];
    const float* W2 = (const float*)d_in[12];
    const float* b2 = (const float*)d_in[13];
    const float* fa = (const float*)d_in[14];
    const float* fb = (const float*)d_in[15];
    const float* Wp = (const float*)d_in[16];
    const float* bp = (const float*)d_in[17];
    float* out = (float*)d_out;   // f32 logits: 2048 x 32000 = 65.536M floats (262MB)

    // memory plan: d_out doubles as scratch (262MB >> 42MB needed).
    //   [0 .. 4MD)  : qb,kb,vb,ob during attention; ff (MROWS*DFF) during FFN
    //   [4MD..5MD)  : x (residual stream) -- dead before final logits write
    // d_ws: hbuf (8MB) -- final GEMM's A operand must live outside d_out.
    const size_t MD = (size_t)MROWS * DMODEL;   // 2,097,152
    float* scratch = out;
    float* qb = scratch;
    float* kb = qb + MD;
    float* vb = kb + MD;
    float* ob = vb + MD;
    float* ff = qb;                  // MROWS*DFF = 4*MD floats, aliases q/k/v/o
    float* x  = scratch + 4 * MD;
    float* hbuf = (float*)d_ws;

    embed_kernel<<<(MROWS * DMODEL + 255) / 256, 256, 0, stream>>>(idx, emb, x);

    dim3 gDD(DMODEL / BN, MROWS / BM);       // 16 x 32
    dim3 gDF(DFF / BN, MROWS / BM);          // 64 x 32
    dim3 gDV(VOCAB / BN, MROWS / BM);        // 500 x 32

    for (int L = 0; L < NLAYERS; ++L) {
        const size_t wDD = (size_t)L * DMODEL * DMODEL;
        ln_kernel<<<MROWS, 256, 0, stream>>>(x, ln1a + (size_t)L * DMODEL, ln1b + (size_t)L * DMODEL, hbuf);
        gemm_kernel<false, false, false><<<gDD, 256, 0, stream>>>(hbuf, Wq + wDD, nullptr, nullptr, qb, DMODEL, DMODEL);
        gemm_kernel<false, false, false><<<gDD, 256, 0, stream>>>(hbuf, Wk + wDD, nullptr, nullptr, kb, DMODEL, DMODEL);
        gemm_kernel<false, false, false><<<gDD, 256, 0, stream>>>(hbuf, Wv + wDD, nullptr, nullptr, vb, DMODEL, DMODEL);
        attn_kernel<<<dim3(TSEQ, NHEADS, BATCH), 64, 0, stream>>>(qb, kb, vb, ob);
        // x = x + o @ Wo   (in-place residual: 1:1 thread->element, safe)
        gemm_kernel<false, false, true><<<gDD, 256, 0, stream>>>(ob, Wo + wDD, nullptr, x, x, DMODEL, DMODEL);
        ln_kernel<<<MROWS, 256, 0, stream>>>(x, ln2a + (size_t)L * DMODEL, ln2b + (size_t)L * DMODEL, hbuf);
        // ff = relu(h @ W1 + b1)   (clobbers q/k/v/o -- dead here)
        gemm_kernel<true, true, false><<<gDF, 256, 0, stream>>>(hbuf, W1 + (size_t)L * DMODEL * DFF, b1 + (size_t)L * DFF, nullptr, ff, DFF, DMODEL);
        // x = x + ff @ W2 + b2
        gemm_kernel<true, false, true><<<gDD, 256, 0, stream>>>(ff, W2 + (size_t)L * DFF * DMODEL, b2 + (size_t)L * DMODEL, x, x, DMODEL, DFF);
    }

    ln_kernel<<<MROWS, 256, 0, stream>>>(x, fa, fb, hbuf);
    // logits = hbuf @ Wp + bp -> f32 over ALL of d_out (scratch dead; A in d_ws)
    gemm_kernel<true, false, false><<<gDV, 256, 0, stream>>>(hbuf, Wp, bp, nullptr, out, VOCAB, DMODEL);
}

// Round 10
// 9931.587 us; speedup vs baseline: 1.5513x; 1.5513x over previous
//
#include <hip/hip_runtime.h>
#include <hip/hip_bf16.h>
#include <math.h>

#define VOCAB 32000
#define TSEQ 1024
#define DMODEL 1024
#define NLAYERS 6
#define NHEADS 16
#define DFF 4096
#define DKH 64
#define BATCH 2
#define MROWS (BATCH * TSEQ)   // 2048
#define LN_EPS 1e-6f

typedef unsigned short u16;
typedef __attribute__((ext_vector_type(8))) short short8v;   // 8 bf16 (4 VGPRs)
typedef __attribute__((ext_vector_type(4))) float f32x4;

__device__ __forceinline__ u16 f2bb(float f) {
    __hip_bfloat16 h = __float2bfloat16(f);
    u16 u; __builtin_memcpy(&u, &h, 2); return u;
}

__device__ __forceinline__ void gload16(const void* g, void* l) {
    __builtin_amdgcn_global_load_lds(
        (const __attribute__((address_space(1))) unsigned int*)g,
        (__attribute__((address_space(3))) unsigned int*)l, 16, 0, 0);
}

// ---------------- embedding + positional encoding ----------------
__global__ void embed_kernel(const int* __restrict__ idx,
                             const float* __restrict__ emb,
                             float* __restrict__ x) {
    int i = blockIdx.x * blockDim.x + threadIdx.x;
    if (i >= MROWS * DMODEL) return;
    int row = i / DMODEL;
    int d = i - row * DMODEL;
    int t = row % TSEQ;
    int tok = idx[row];
    float e = emb[(size_t)tok * DMODEL + d] * 32.0f;
    float freq = expf(-(float)(d & ~1) * (9.210340371976184f / (float)DMODEL));
    float ang = (float)t * freq;
    float pe = (d & 1) ? cosf(ang) : sinf(ang);
    x[i] = e + pe;
}

// ---------------- layernorm (ddof=1, denom = std + eps); bf16 or f32 out ----------------
template<bool OB16>
__global__ void __launch_bounds__(256) ln_kernel(const float* __restrict__ x,
                                                 const float* __restrict__ a,
                                                 const float* __restrict__ b,
                                                 void* __restrict__ yv) {
    __shared__ float red[8];
    int row = blockIdx.x;
    int tid = threadIdx.x;
    float4 v = ((const float4*)(x + (size_t)row * DMODEL))[tid];
    float s = v.x + v.y + v.z + v.w;
    #pragma unroll
    for (int off = 32; off; off >>= 1) s += __shfl_xor(s, off, 64);
    if ((tid & 63) == 0) red[tid >> 6] = s;
    __syncthreads();
    float mean = (red[0] + red[1] + red[2] + red[3]) * (1.0f / DMODEL);
    float dx = v.x - mean, dy = v.y - mean, dz = v.z - mean, dw = v.w - mean;
    float ss = dx * dx + dy * dy + dz * dz + dw * dw;
    #pragma unroll
    for (int off = 32; off; off >>= 1) ss += __shfl_xor(ss, off, 64);
    if ((tid & 63) == 0) red[4 + (tid >> 6)] = ss;
    __syncthreads();
    float var = (red[4] + red[5] + red[6] + red[7]) * (1.0f / (DMODEL - 1));
    float inv = 1.0f / (sqrtf(var) + LN_EPS);
    const float4 a4 = ((const float4*)a)[tid];
    const float4 b4 = ((const float4*)b)[tid];
    float o0 = a4.x * dx * inv + b4.x;
    float o1 = a4.y * dy * inv + b4.y;
    float o2 = a4.z * dz * inv + b4.z;
    float o3 = a4.w * dw * inv + b4.w;
    if (OB16) {
        ushort4 o; o.x = f2bb(o0); o.y = f2bb(o1); o.z = f2bb(o2); o.w = f2bb(o3);
        ((ushort4*)((u16*)yv + (size_t)row * DMODEL))[tid] = o;
    } else {
        float4 o; o.x = o0; o.y = o1; o.z = o2; o.w = o3;
        ((float4*)((float*)yv + (size_t)row * DMODEL))[tid] = o;
    }
}

// ---------------- transpose-convert: in f32 [K,N] -> out bf16 [N,K] ----------------
__global__ void __launch_bounds__(256) convT(const float* __restrict__ in,
                                             u16* __restrict__ out, int K, int N) {
    __shared__ float t[32][33];
    in  += (size_t)blockIdx.z * K * N;
    out += (size_t)blockIdx.z * K * N;
    const int tx = threadIdx.x, ty = threadIdx.y;  // block (32,8)
    const int n0 = blockIdx.x * 32, k0 = blockIdx.y * 32;
    #pragma unroll
    for (int i = 0; i < 4; ++i)
        t[ty + i * 8][tx] = in[(size_t)(k0 + ty + i * 8) * N + n0 + tx];
    __syncthreads();
    #pragma unroll
    for (int i = 0; i < 4; ++i)
        out[(size_t)(n0 + ty + i * 8) * K + k0 + tx] = f2bb(t[tx][ty + i * 8]);
}

// ---------------- MFMA GEMM: C[M,N] = A_bf16[M,K] @ (Bt_bf16[N,K])^T + epilogue ----------------
// 128x128 tile, BK=32, 256 threads (4 waves, each 64x64 quadrant), 16x16x32 bf16 MFMA
template<bool BIAS, bool RELU, bool RES, bool OB16>
__global__ void __launch_bounds__(256) gemm_mfma(
    const u16* __restrict__ A, const u16* __restrict__ Bt,
    const float* __restrict__ bias, const float* res,
    void* outp, int N, int K)
{
    __shared__ u16 Alds[128 * 32];
    __shared__ u16 Blds[128 * 32];
    const int tid = threadIdx.x;
    const int w = tid >> 6, lane = tid & 63;
    const int wr = w >> 1, wc = w & 1;
    const size_t bm = (size_t)blockIdx.y * 128, bn = (size_t)blockIdx.x * 128;
    const int srow = (w << 4) + (lane >> 2);      // staging row (+ li*64)
    const int scol = (lane & 3) << 3;             // staging k-offset (bf16)
    const int fr = lane & 15, fq = lane >> 4;     // fragment row / k-quarter

    f32x4 acc[4][4];
    #pragma unroll
    for (int m = 0; m < 4; ++m)
        #pragma unroll
        for (int n = 0; n < 4; ++n)
            acc[m][n] = (f32x4){0.f, 0.f, 0.f, 0.f};

    for (int k0 = 0; k0 < K; k0 += 32) {
        #pragma unroll
        for (int li = 0; li < 2; ++li) {
            gload16(A  + (bm + li * 64 + srow) * K + k0 + scol, Alds + li * 2048 + w * 512);
            gload16(Bt + (bn + li * 64 + srow) * K + k0 + scol, Blds + li * 2048 + w * 512);
        }
        __syncthreads();   // drains vmcnt before barrier -> tiles visible
        short8v a[4], b[4];
        #pragma unroll
        for (int m = 0; m < 4; ++m)
            a[m] = *(const short8v*)(Alds + (wr * 64 + m * 16 + fr) * 32 + fq * 8);
        #pragma unroll
        for (int n = 0; n < 4; ++n)
            b[n] = *(const short8v*)(Blds + (wc * 64 + n * 16 + fr) * 32 + fq * 8);
        #pragma unroll
        for (int m = 0; m < 4; ++m)
            #pragma unroll
            for (int n = 0; n < 4; ++n)
                acc[m][n] = __builtin_amdgcn_mfma_f32_16x16x32_bf16(a[m], b[n], acc[m][n], 0, 0, 0);
        __syncthreads();   // protect LDS from next-step staging
    }

    #pragma unroll
    for (int n = 0; n < 4; ++n) {
        const size_t col = bn + wc * 64 + n * 16 + fr;
        const float bv = BIAS ? bias[col] : 0.f;
        #pragma unroll
        for (int m = 0; m < 4; ++m) {
            #pragma unroll
            for (int r = 0; r < 4; ++r) {
                const size_t row = bm + wr * 64 + m * 16 + fq * 4 + r;
                float v = acc[m][n][r] + bv;
                if (RELU) v = fmaxf(v, 0.f);
                if (RES)  v += res[row * N + col];
                if (OB16) ((u16*)outp)[row * N + col] = f2bb(v);
                else      ((float*)outp)[row * N + col] = v;
            }
        }
    }
}

// ---------------- f32 GEMM (fallback vocab path only) ----------------
#define BM 64
#define BN 64
#define BK 16
__global__ void __launch_bounds__(256) gemm_f32(
    const float* __restrict__ A, const float* __restrict__ Bw,
    const float* __restrict__ bias, float* outp, int N, int K)
{
    __shared__ float As[BK][BM];
    __shared__ float Bs[BK][BN];
    const int bm = blockIdx.y * BM, bn = blockIdx.x * BN;
    const int tid = threadIdx.x;
    const int tr = (tid >> 4) << 2, tc = (tid & 15) << 2;
    const int am = tid >> 2, ak = (tid & 3) << 2;
    const int bk = tid >> 4, bn4 = (tid & 15) << 2;
    float acc[4][4] = {};
    const float* Ap = A + (size_t)(bm + am) * K + ak;
    const float* Bp = Bw + (size_t)bk * N + bn + bn4;
    for (int k0 = 0; k0 < K; k0 += BK) {
        float4 av = *(const float4*)(Ap + k0);
        float4 bv = *(const float4*)(Bp + (size_t)k0 * N);
        As[ak + 0][am] = av.x; As[ak + 1][am] = av.y; As[ak + 2][am] = av.z; As[ak + 3][am] = av.w;
        *(float4*)&Bs[bk][bn4] = bv;
        __syncthreads();
        #pragma unroll
        for (int kk = 0; kk < BK; ++kk) {
            float4 a4 = *(const float4*)&As[kk][tr];
            float4 b4 = *(const float4*)&Bs[kk][tc];
            acc[0][0] += a4.x*b4.x; acc[0][1] += a4.x*b4.y; acc[0][2] += a4.x*b4.z; acc[0][3] += a4.x*b4.w;
            acc[1][0] += a4.y*b4.x; acc[1][1] += a4.y*b4.y; acc[1][2] += a4.y*b4.z; acc[1][3] += a4.y*b4.w;
            acc[2][0] += a4.z*b4.x; acc[2][1] += a4.z*b4.y; acc[2][2] += a4.z*b4.z; acc[2][3] += a4.z*b4.w;
            acc[3][0] += a4.w*b4.x; acc[3][1] += a4.w*b4.y; acc[3][2] += a4.w*b4.z; acc[3][3] += a4.w*b4.w;
        }
        __syncthreads();
    }
    #pragma unroll
    for (int i = 0; i < 4; ++i) {
        int row = bm + tr + i;
        float4 o;
        o.x = acc[i][0] + bias[bn + tc + 0];
        o.y = acc[i][1] + bias[bn + tc + 1];
        o.z = acc[i][2] + bias[bn + tc + 2];
        o.w = acc[i][3] + bias[bn + tc + 3];
        *(float4*)(outp + (size_t)row * N + bn + tc) = o;
    }
}

// ---------------- attention: one wave per (b,h,qi), online softmax; bf16 out ----------------
__global__ void __launch_bounds__(64) attn_kernel(const float* __restrict__ q,
                                                  const float* __restrict__ k,
                                                  const float* __restrict__ v,
                                                  u16* __restrict__ o) {
    int lane = threadIdx.x;
    int qi = blockIdx.x;
    int h = blockIdx.y;
    int b = blockIdx.z;
    const size_t base = (size_t)b * TSEQ * DMODEL + h * DKH;
    float qd = q[base + (size_t)qi * DMODEL + lane];
    float m = -1e30f, l = 0.f, od = 0.f;
    for (int j = 0; j <= qi; ++j) {
        float kd = k[base + (size_t)j * DMODEL + lane];
        float s = qd * kd;
        #pragma unroll
        for (int off = 32; off; off >>= 1) s += __shfl_xor(s, off, 64);
        s *= 0.125f;
        float mn = fmaxf(m, s);
        float c = __expf(m - mn);
        float p = __expf(s - mn);
        float vd = v[base + (size_t)j * DMODEL + lane];
        l = l * c + p;
        od = od * c + p * vd;
        m = mn;
    }
    o[base + (size_t)qi * DMODEL + lane] = f2bb(od / l);
}

// ---------------- host ----------------
extern "C" void kernel_launch(void* const* d_in, const int* in_sizes, int n_in,
                              void* d_out, int out_size, void* d_ws, size_t ws_size,
                              hipStream_t stream) {
    const int* idx = (const int*)d_in[0];
    const float* emb = (const float*)d_in[1];
    const float* Wq = (const float*)d_in[2];
    const float* Wk = (const float*)d_in[3];
    const float* Wv = (const float*)d_in[4];
    const float* Wo = (const float*)d_in[5];
    const float* ln1a = (const float*)d_in[6];
    const float* ln1b = (const float*)d_in[7];
    const float* ln2a = (const float*)d_in[8];
    const float* ln2b = (const float*)d_in[9];
    const float* W1 = (const float*)d_in[10];
    const float* b1 = (const float*)d_in[11];
    const float* W2 = (const float*)d_in[12];
    const float* b2 = (const float*)d_in[13];
    const float* fa = (const float*)d_in[14];
    const float* fb = (const float*)d_in[15];
    const float* Wp = (const float*)d_in[16];
    const float* bp = (const float*)d_in[17];
    float* out = (float*)d_out;   // f32 logits, 262MB

    // ---- d_out-as-scratch layout (floats; MD = 2048*1024) ----
    //  [0,3MD)   qb,kb,vb f32     [3MD,3.5MD) ob bf16    [3.5MD,4MD) h bf16
    //  [4MD,5MD) x f32            [5MD,7MD)   ff bf16
    //  [7MD,13MD) WqkvoT bf16     [13MD,19MD) W1T bf16   [19MD,25MD) W2T bf16
    // all dead before the final logits write.
    const size_t MD = (size_t)MROWS * DMODEL;
    const size_t MM = (size_t)DMODEL * DMODEL;
    float* scratch = out;
    float* qb = scratch;
    float* kb = qb + MD;
    float* vb = kb + MD;
    u16*   ob = (u16*)(scratch + 3 * MD);
    u16*   hb = (u16*)(scratch + 3 * MD) + MD;          // h bf16
    float* x  = scratch + 4 * MD;
    u16*   ff = (u16*)(scratch + 5 * MD);
    u16*   WqT = (u16*)(scratch + 7 * MD);
    u16*   WkT = WqT + 6 * MM;
    u16*   WvT = WkT + 6 * MM;
    u16*   WoT = WvT + 6 * MM;
    u16*   W1T = (u16*)(scratch + 13 * MD);             // 6 x [4096,1024]
    u16*   W2T = (u16*)(scratch + 19 * MD);             // 6 x [1024,4096]

    // final-GEMM operands must survive the d_out write -> d_ws (needs 68MB)
    const bool pathA = ws_size >= (size_t)68 * 1024 * 1024 + 256;
    u16* WpT = (u16*)d_ws;                               // [32000,1024] bf16, 64MB
    u16* h2b = (u16*)((char*)d_ws + (size_t)64 * 1024 * 1024);  // 4MB
    float* hF = (float*)d_ws;                            // path B: f32 h, 8MB

    dim3 cblk(32, 8);
    convT<<<dim3(32, 32, 6), cblk, 0, stream>>>(Wq, WqT, DMODEL, DMODEL);
    convT<<<dim3(32, 32, 6), cblk, 0, stream>>>(Wk, WkT, DMODEL, DMODEL);
    convT<<<dim3(32, 32, 6), cblk, 0, stream>>>(Wv, WvT, DMODEL, DMODEL);
    convT<<<dim3(32, 32, 6), cblk, 0, stream>>>(Wo, WoT, DMODEL, DMODEL);
    convT<<<dim3(128, 32, 6), cblk, 0, stream>>>(W1, W1T, DMODEL, DFF);
    convT<<<dim3(32, 128, 6), cblk, 0, stream>>>(W2, W2T, DFF, DMODEL);
    if (pathA) convT<<<dim3(1000, 32, 1), cblk, 0, stream>>>(Wp, WpT, DMODEL, VOCAB);

    embed_kernel<<<(MROWS * DMODEL + 255) / 256, 256, 0, stream>>>(idx, emb, x);

    dim3 gDD(DMODEL / 128, MROWS / 128);   // 8 x 16
    dim3 gDF(DFF / 128, MROWS / 128);      // 32 x 16
    dim3 gDV(VOCAB / 128, MROWS / 128);    // 250 x 16

    for (int L = 0; L < NLAYERS; ++L) {
        ln_kernel<true><<<MROWS, 256, 0, stream>>>(x, ln1a + (size_t)L * DMODEL, ln1b + (size_t)L * DMODEL, hb);
        gemm_mfma<false, false, false, false><<<gDD, 256, 0, stream>>>(hb, WqT + (size_t)L * MM, nullptr, nullptr, qb, DMODEL, DMODEL);
        gemm_mfma<false, false, false, false><<<gDD, 256, 0, stream>>>(hb, WkT + (size_t)L * MM, nullptr, nullptr, kb, DMODEL, DMODEL);
        gemm_mfma<false, false, false, false><<<gDD, 256, 0, stream>>>(hb, WvT + (size_t)L * MM, nullptr, nullptr, vb, DMODEL, DMODEL);
        attn_kernel<<<dim3(TSEQ, NHEADS, BATCH), 64, 0, stream>>>(qb, kb, vb, ob);
        // x = x + ob @ WoT^T (in-place residual, 1:1)
        gemm_mfma<false, false, true, false><<<gDD, 256, 0, stream>>>(ob, WoT + (size_t)L * MM, nullptr, x, x, DMODEL, DMODEL);
        ln_kernel<true><<<MROWS, 256, 0, stream>>>(x, ln2a + (size_t)L * DMODEL, ln2b + (size_t)L * DMODEL, hb);
        // ff = relu(h @ W1 + b1) -> bf16
        gemm_mfma<true, true, false, true><<<gDF, 256, 0, stream>>>(hb, W1T + (size_t)L * DFF * DMODEL, b1 + (size_t)L * DFF, nullptr, ff, DFF, DMODEL);
        // x = x + ff @ W2 + b2
        gemm_mfma<true, false, true, false><<<gDD, 256, 0, stream>>>(ff, W2T + (size_t)L * DFF * DMODEL, b2 + (size_t)L * DMODEL, x, x, DMODEL, DFF);
    }

    if (pathA) {
        ln_kernel<true><<<MROWS, 256, 0, stream>>>(x, fa, fb, h2b);
        gemm_mfma<true, false, false, false><<<gDV, 256, 0, stream>>>(h2b, WpT, bp, nullptr, out, VOCAB, DMODEL);
    } else {
        ln_kernel<false><<<MROWS, 256, 0, stream>>>(x, fa, fb, hF);
        gemm_f32<<<dim3(VOCAB / BN, MROWS / BM), 256, 0, stream>>>(hF, Wp, bp, out, VOCAB, DMODEL);
    }
}

// Round 11
// 2489.045 us; speedup vs baseline: 6.1899x; 3.9901x over previous
//
#include <hip/hip_runtime.h>
#include <hip/hip_bf16.h>
#include <math.h>

#define VOCAB 32000
#define TSEQ 1024
#define DMODEL 1024
#define NLAYERS 6
#define NHEADS 16
#define DFF 4096
#define DKH 64
#define BATCH 2
#define MROWS (BATCH * TSEQ)   // 2048
#define LN_EPS 1e-6f

typedef unsigned short u16;
typedef __attribute__((ext_vector_type(8))) short short8v;   // 8 bf16 (4 VGPRs)
typedef __attribute__((ext_vector_type(4))) float f32x4;

__device__ __forceinline__ u16 f2bb(float f) {
    __hip_bfloat16 h = __float2bfloat16(f);
    u16 u; __builtin_memcpy(&u, &h, 2); return u;
}

__device__ __forceinline__ void gload16(const void* g, void* l) {
    __builtin_amdgcn_global_load_lds(
        (const __attribute__((address_space(1))) unsigned int*)g,
        (__attribute__((address_space(3))) unsigned int*)l, 16, 0, 0);
}

// ---------------- embedding + positional encoding ----------------
__global__ void embed_kernel(const int* __restrict__ idx,
                             const float* __restrict__ emb,
                             float* __restrict__ x) {
    int i = blockIdx.x * blockDim.x + threadIdx.x;
    if (i >= MROWS * DMODEL) return;
    int row = i / DMODEL;
    int d = i - row * DMODEL;
    int t = row % TSEQ;
    int tok = idx[row];
    float e = emb[(size_t)tok * DMODEL + d] * 32.0f;
    float freq = expf(-(float)(d & ~1) * (9.210340371976184f / (float)DMODEL));
    float ang = (float)t * freq;
    float pe = (d & 1) ? cosf(ang) : sinf(ang);
    x[i] = e + pe;
}

// ---------------- layernorm (ddof=1, denom = std + eps); bf16 or f32 out ----------------
template<bool OB16>
__global__ void __launch_bounds__(256) ln_kernel(const float* __restrict__ x,
                                                 const float* __restrict__ a,
                                                 const float* __restrict__ b,
                                                 void* __restrict__ yv) {
    __shared__ float red[8];
    int row = blockIdx.x;
    int tid = threadIdx.x;
    float4 v = ((const float4*)(x + (size_t)row * DMODEL))[tid];
    float s = v.x + v.y + v.z + v.w;
    #pragma unroll
    for (int off = 32; off; off >>= 1) s += __shfl_xor(s, off, 64);
    if ((tid & 63) == 0) red[tid >> 6] = s;
    __syncthreads();
    float mean = (red[0] + red[1] + red[2] + red[3]) * (1.0f / DMODEL);
    float dx = v.x - mean, dy = v.y - mean, dz = v.z - mean, dw = v.w - mean;
    float ss = dx * dx + dy * dy + dz * dz + dw * dw;
    #pragma unroll
    for (int off = 32; off; off >>= 1) ss += __shfl_xor(ss, off, 64);
    if ((tid & 63) == 0) red[4 + (tid >> 6)] = ss;
    __syncthreads();
    float var = (red[4] + red[5] + red[6] + red[7]) * (1.0f / (DMODEL - 1));
    float inv = 1.0f / (sqrtf(var) + LN_EPS);
    const float4 a4 = ((const float4*)a)[tid];
    const float4 b4 = ((const float4*)b)[tid];
    float o0 = a4.x * dx * inv + b4.x;
    float o1 = a4.y * dy * inv + b4.y;
    float o2 = a4.z * dz * inv + b4.z;
    float o3 = a4.w * dw * inv + b4.w;
    if (OB16) {
        ushort4 o; o.x = f2bb(o0); o.y = f2bb(o1); o.z = f2bb(o2); o.w = f2bb(o3);
        ((ushort4*)((u16*)yv + (size_t)row * DMODEL))[tid] = o;
    } else {
        float4 o; o.x = o0; o.y = o1; o.z = o2; o.w = o3;
        ((float4*)((float*)yv + (size_t)row * DMODEL))[tid] = o;
    }
}

// ---------------- transpose-convert: in f32 [K,N] -> out bf16 [N,K] ----------------
__global__ void __launch_bounds__(256) convT(const float* __restrict__ in,
                                             u16* __restrict__ out, int K, int N) {
    __shared__ float t[32][33];
    in  += (size_t)blockIdx.z * K * N;
    out += (size_t)blockIdx.z * K * N;
    const int tx = threadIdx.x, ty = threadIdx.y;  // block (32,8)
    const int n0 = blockIdx.x * 32, k0 = blockIdx.y * 32;
    #pragma unroll
    for (int i = 0; i < 4; ++i)
        t[ty + i * 8][tx] = in[(size_t)(k0 + ty + i * 8) * N + n0 + tx];
    __syncthreads();
    #pragma unroll
    for (int i = 0; i < 4; ++i)
        out[(size_t)(n0 + ty + i * 8) * K + k0 + tx] = f2bb(t[tx][ty + i * 8]);
}

// ---------------- MFMA GEMM: C[M,N] = A_bf16[M,K] @ (Bt_bf16[N,K])^T + epilogue ----------------
template<bool BIAS, bool RELU, bool RES, bool OB16>
__global__ void __launch_bounds__(256) gemm_mfma(
    const u16* __restrict__ A, const u16* __restrict__ Bt,
    const float* __restrict__ bias, const float* res,
    void* outp, int N, int K)
{
    __shared__ u16 Alds[128 * 32];
    __shared__ u16 Blds[128 * 32];
    const int tid = threadIdx.x;
    const int w = tid >> 6, lane = tid & 63;
    const int wr = w >> 1, wc = w & 1;
    const size_t bm = (size_t)blockIdx.y * 128, bn = (size_t)blockIdx.x * 128;
    const int srow = (w << 4) + (lane >> 2);
    const int scol = (lane & 3) << 3;
    const int fr = lane & 15, fq = lane >> 4;

    f32x4 acc[4][4];
    #pragma unroll
    for (int m = 0; m < 4; ++m)
        #pragma unroll
        for (int n = 0; n < 4; ++n)
            acc[m][n] = (f32x4){0.f, 0.f, 0.f, 0.f};

    for (int k0 = 0; k0 < K; k0 += 32) {
        #pragma unroll
        for (int li = 0; li < 2; ++li) {
            gload16(A  + (bm + li * 64 + srow) * K + k0 + scol, Alds + li * 2048 + w * 512);
            gload16(Bt + (bn + li * 64 + srow) * K + k0 + scol, Blds + li * 2048 + w * 512);
        }
        __syncthreads();
        short8v a[4], b[4];
        #pragma unroll
        for (int m = 0; m < 4; ++m)
            a[m] = *(const short8v*)(Alds + (wr * 64 + m * 16 + fr) * 32 + fq * 8);
        #pragma unroll
        for (int n = 0; n < 4; ++n)
            b[n] = *(const short8v*)(Blds + (wc * 64 + n * 16 + fr) * 32 + fq * 8);
        #pragma unroll
        for (int m = 0; m < 4; ++m)
            #pragma unroll
            for (int n = 0; n < 4; ++n)
                acc[m][n] = __builtin_amdgcn_mfma_f32_16x16x32_bf16(a[m], b[n], acc[m][n], 0, 0, 0);
        __syncthreads();
    }

    #pragma unroll
    for (int n = 0; n < 4; ++n) {
        const size_t col = bn + wc * 64 + n * 16 + fr;
        const float bv = BIAS ? bias[col] : 0.f;
        #pragma unroll
        for (int m = 0; m < 4; ++m) {
            #pragma unroll
            for (int r = 0; r < 4; ++r) {
                const size_t row = bm + wr * 64 + m * 16 + fq * 4 + r;
                float v = acc[m][n][r] + bv;
                if (RELU) v = fmaxf(v, 0.f);
                if (RES)  v += res[row * N + col];
                if (OB16) ((u16*)outp)[row * N + col] = f2bb(v);
                else      ((float*)outp)[row * N + col] = v;
            }
        }
    }
}

// ---------------- flash attention: block = (b,h,64 q-rows), 4 waves x 16 rows ----------------
// KVBLK=32. S via mfma(Q,K); online softmax in regs; P->LDS relayout; PV via mfma(P,Vt).
__global__ void __launch_bounds__(256) attn_flash(const u16* __restrict__ q,
                                                  const u16* __restrict__ k,
                                                  const u16* __restrict__ v,
                                                  u16* __restrict__ o) {
    __shared__ u16 Klds[32 * 64];        // [kj][d], rows 128B, XOR-swizzled
    __shared__ u16 Vt[64 * 40];          // [d][kj], rows padded to 80B
    __shared__ u16 Plds[4][16 * 40];     // per-wave [q16][kj32], rows padded 80B

    const int tid = threadIdx.x;
    const int w = tid >> 6, lane = tid & 63;
    const int fr = lane & 15, fq = lane >> 4;
    const int qt = blockIdx.x, h = blockIdx.y, b = blockIdx.z;
    const int qbase = qt * 64 + w * 16;
    const size_t rowbase = (size_t)b * TSEQ;
    const int hd = h * DKH;

    // Q fragments in registers: Q[fr][fq*8..+7] for both d-halves
    const u16* qrow = q + (rowbase + qbase + fr) * DMODEL + hd;
    const short8v qf0 = *(const short8v*)(qrow + fq * 8);
    const short8v qf1 = *(const short8v*)(qrow + 32 + fq * 8);

    float m[4], l[4];
    f32x4 oa[4];                         // oa[nd][r]
    #pragma unroll
    for (int r = 0; r < 4; ++r) { m[r] = -1e30f; l[r] = 0.f; }
    #pragma unroll
    for (int nd = 0; nd < 4; ++nd) oa[nd] = (f32x4){0.f, 0.f, 0.f, 0.f};

    const int ntiles = qt * 2 + 2;
    for (int t = 0; t < ntiles; ++t) {
        const int j0 = t * 32;
        // ---- stage K (swizzled) and Vt (transposed) ----
        {
            const int r = tid >> 3, c8 = (tid & 7) << 3;
            const size_t grow = (rowbase + j0 + r) * DMODEL + hd + c8;
            short8v kv = *(const short8v*)(k + grow);
            int kbyte = (r * 128 + c8 * 2) ^ ((r & 7) << 4);
            *(short8v*)((char*)Klds + kbyte) = kv;
            short8v vv = *(const short8v*)(v + grow);
            #pragma unroll
            for (int i = 0; i < 8; ++i)
                Vt[(c8 + i) * 40 + r] = (u16)vv[i];
        }
        __syncthreads();

        if (j0 <= qbase + 15) {
            // ---- S = Q K^T (2 col-tiles x 2 d-halves) ----
            f32x4 s[2];
            #pragma unroll
            for (int ct = 0; ct < 2; ++ct) {
                const int krow = ct * 16 + fr;
                const int swz = (krow & 7) << 4;
                short8v k0 = *(const short8v*)((char*)Klds + ((krow * 128 + fq * 16) ^ swz));
                short8v k1 = *(const short8v*)((char*)Klds + ((krow * 128 + 64 + fq * 16) ^ swz));
                f32x4 a = (f32x4){0.f, 0.f, 0.f, 0.f};
                a = __builtin_amdgcn_mfma_f32_16x16x32_bf16(qf0, k0, a, 0, 0, 0);
                a = __builtin_amdgcn_mfma_f32_16x16x32_bf16(qf1, k1, a, 0, 0, 0);
                s[ct] = a;
            }
            // ---- mask + online softmax (rows q = fq*4+r, col kj = ct*16+fr) ----
            float c[4];
            #pragma unroll
            for (int r = 0; r < 4; ++r) {
                const int qg = qbase + fq * 4 + r;
                float s0 = s[0][r] * 0.125f;
                float s1 = s[1][r] * 0.125f;
                if (j0 + fr      > qg) s0 = -1e30f;
                if (j0 + 16 + fr > qg) s1 = -1e30f;
                float mx = fmaxf(s0, s1);
                mx = fmaxf(mx, __shfl_xor(mx, 1, 64));
                mx = fmaxf(mx, __shfl_xor(mx, 2, 64));
                mx = fmaxf(mx, __shfl_xor(mx, 4, 64));
                mx = fmaxf(mx, __shfl_xor(mx, 8, 64));
                const float mn = fmaxf(m[r], mx);
                c[r] = __expf(m[r] - mn);
                m[r] = mn;
                const float p0 = __expf(s0 - mn);
                const float p1 = __expf(s1 - mn);
                float rs = p0 + p1;
                rs += __shfl_xor(rs, 1, 64);
                rs += __shfl_xor(rs, 2, 64);
                rs += __shfl_xor(rs, 4, 64);
                rs += __shfl_xor(rs, 8, 64);
                l[r] = l[r] * c[r] + rs;
                Plds[w][(fq * 4 + r) * 40 + fr]      = f2bb(p0);
                Plds[w][(fq * 4 + r) * 40 + 16 + fr] = f2bb(p1);
            }
            #pragma unroll
            for (int nd = 0; nd < 4; ++nd)
                #pragma unroll
                for (int r = 0; r < 4; ++r)
                    oa[nd][r] *= c[r];
            // wave-local: ensure P writes landed before relayout read
            asm volatile("s_waitcnt lgkmcnt(0)" ::: "memory");
            __builtin_amdgcn_sched_barrier(0);
            // ---- PV: A-frag = P[fr][fq*8..+7], B-frag = Vt[nd*16+fr][fq*8..+7] ----
            const short8v pf = *(const short8v*)(&Plds[w][fr * 40 + fq * 8]);
            #pragma unroll
            for (int nd = 0; nd < 4; ++nd) {
                const short8v vf = *(const short8v*)(&Vt[(nd * 16 + fr) * 40 + fq * 8]);
                oa[nd] = __builtin_amdgcn_mfma_f32_16x16x32_bf16(pf, vf, oa[nd], 0, 0, 0);
            }
        }
        __syncthreads();
    }

    // ---- output: rows q = fq*4+r, cols d = nd*16+fr ----
    #pragma unroll
    for (int r = 0; r < 4; ++r) {
        const float inv = 1.0f / l[r];
        u16* orow = o + (rowbase + qbase + fq * 4 + r) * DMODEL + hd;
        #pragma unroll
        for (int nd = 0; nd < 4; ++nd)
            orow[nd * 16 + fr] = f2bb(oa[nd][r] * inv);
    }
}

// ---------------- f32 GEMM (fallback vocab path only) ----------------
#define BM 64
#define BN 64
#define BK 16
__global__ void __launch_bounds__(256) gemm_f32(
    const float* __restrict__ A, const float* __restrict__ Bw,
    const float* __restrict__ bias, float* outp, int N, int K)
{
    __shared__ float As[BK][BM];
    __shared__ float Bs[BK][BN];
    const int bm = blockIdx.y * BM, bn = blockIdx.x * BN;
    const int tid = threadIdx.x;
    const int tr = (tid >> 4) << 2, tc = (tid & 15) << 2;
    const int am = tid >> 2, ak = (tid & 3) << 2;
    const int bk = tid >> 4, bn4 = (tid & 15) << 2;
    float acc[4][4] = {};
    const float* Ap = A + (size_t)(bm + am) * K + ak;
    const float* Bp = Bw + (size_t)bk * N + bn + bn4;
    for (int k0 = 0; k0 < K; k0 += BK) {
        float4 av = *(const float4*)(Ap + k0);
        float4 bv = *(const float4*)(Bp + (size_t)k0 * N);
        As[ak + 0][am] = av.x; As[ak + 1][am] = av.y; As[ak + 2][am] = av.z; As[ak + 3][am] = av.w;
        *(float4*)&Bs[bk][bn4] = bv;
        __syncthreads();
        #pragma unroll
        for (int kk = 0; kk < BK; ++kk) {
            float4 a4 = *(const float4*)&As[kk][tr];
            float4 b4 = *(const float4*)&Bs[kk][tc];
            acc[0][0] += a4.x*b4.x; acc[0][1] += a4.x*b4.y; acc[0][2] += a4.x*b4.z; acc[0][3] += a4.x*b4.w;
            acc[1][0] += a4.y*b4.x; acc[1][1] += a4.y*b4.y; acc[1][2] += a4.y*b4.z; acc[1][3] += a4.y*b4.w;
            acc[2][0] += a4.z*b4.x; acc[2][1] += a4.z*b4.y; acc[2][2] += a4.z*b4.z; acc[2][3] += a4.z*b4.w;
            acc[3][0] += a4.w*b4.x; acc[3][1] += a4.w*b4.y; acc[3][2] += a4.w*b4.z; acc[3][3] += a4.w*b4.w;
        }
        __syncthreads();
    }
    #pragma unroll
    for (int i = 0; i < 4; ++i) {
        int row = bm + tr + i;
        float4 o;
        o.x = acc[i][0] + bias[bn + tc + 0];
        o.y = acc[i][1] + bias[bn + tc + 1];
        o.z = acc[i][2] + bias[bn + tc + 2];
        o.w = acc[i][3] + bias[bn + tc + 3];
        *(float4*)(outp + (size_t)row * N + bn + tc) = o;
    }
}

// ---------------- host ----------------
extern "C" void kernel_launch(void* const* d_in, const int* in_sizes, int n_in,
                              void* d_out, int out_size, void* d_ws, size_t ws_size,
                              hipStream_t stream) {
    const int* idx = (const int*)d_in[0];
    const float* emb = (const float*)d_in[1];
    const float* Wq = (const float*)d_in[2];
    const float* Wk = (const float*)d_in[3];
    const float* Wv = (const float*)d_in[4];
    const float* Wo = (const float*)d_in[5];
    const float* ln1a = (const float*)d_in[6];
    const float* ln1b = (const float*)d_in[7];
    const float* ln2a = (const float*)d_in[8];
    const float* ln2b = (const float*)d_in[9];
    const float* W1 = (const float*)d_in[10];
    const float* b1 = (const float*)d_in[11];
    const float* W2 = (const float*)d_in[12];
    const float* b2 = (const float*)d_in[13];
    const float* fa = (const float*)d_in[14];
    const float* fb = (const float*)d_in[15];
    const float* Wp = (const float*)d_in[16];
    const float* bp = (const float*)d_in[17];
    float* out = (float*)d_out;   // f32 logits (262MB)

    // ---- d_out-as-scratch, u16 units (MD = 2M) ----
    // [0,5MD): qb,kb,vb,ob,hb bf16 | [5MD,7MD): x f32 | [7MD,11MD): ff bf16
    // [12MD,24MD): WqkvoT | [24MD,36MD): W1T | [36MD,48MD): W2T   (96MB < 262MB)
    const size_t MD = (size_t)MROWS * DMODEL;
    const size_t MM = (size_t)DMODEL * DMODEL;
    u16* U = (u16*)out;
    u16* qb = U;
    u16* kb = U + MD;
    u16* vb = U + 2 * MD;
    u16* ob = U + 3 * MD;
    u16* hb = U + 4 * MD;
    float* x = (float*)(U + 5 * MD);
    u16* ff = U + 7 * MD;
    u16* WqT = U + 12 * MD;
    u16* WkT = WqT + 6 * MM;
    u16* WvT = WkT + 6 * MM;
    u16* WoT = WvT + 6 * MM;
    u16* W1T = U + 24 * MD;
    u16* W2T = U + 36 * MD;

    const bool pathA = ws_size >= (size_t)68 * 1024 * 1024 + 256;
    u16* WpT = (u16*)d_ws;
    u16* h2b = (u16*)((char*)d_ws + (size_t)64 * 1024 * 1024);
    float* hF = (float*)d_ws;

    dim3 cblk(32, 8);
    convT<<<dim3(32, 32, 6), cblk, 0, stream>>>(Wq, WqT, DMODEL, DMODEL);
    convT<<<dim3(32, 32, 6), cblk, 0, stream>>>(Wk, WkT, DMODEL, DMODEL);
    convT<<<dim3(32, 32, 6), cblk, 0, stream>>>(Wv, WvT, DMODEL, DMODEL);
    convT<<<dim3(32, 32, 6), cblk, 0, stream>>>(Wo, WoT, DMODEL, DMODEL);
    convT<<<dim3(128, 32, 6), cblk, 0, stream>>>(W1, W1T, DMODEL, DFF);
    convT<<<dim3(32, 128, 6), cblk, 0, stream>>>(W2, W2T, DFF, DMODEL);
    if (pathA) convT<<<dim3(1000, 32, 1), cblk, 0, stream>>>(Wp, WpT, DMODEL, VOCAB);

    embed_kernel<<<(MROWS * DMODEL + 255) / 256, 256, 0, stream>>>(idx, emb, x);

    dim3 gDD(DMODEL / 128, MROWS / 128);
    dim3 gDF(DFF / 128, MROWS / 128);
    dim3 gDV(VOCAB / 128, MROWS / 128);

    for (int L = 0; L < NLAYERS; ++L) {
        ln_kernel<true><<<MROWS, 256, 0, stream>>>(x, ln1a + (size_t)L * DMODEL, ln1b + (size_t)L * DMODEL, hb);
        gemm_mfma<false, false, false, true><<<gDD, 256, 0, stream>>>(hb, WqT + (size_t)L * MM, nullptr, nullptr, qb, DMODEL, DMODEL);
        gemm_mfma<false, false, false, true><<<gDD, 256, 0, stream>>>(hb, WkT + (size_t)L * MM, nullptr, nullptr, kb, DMODEL, DMODEL);
        gemm_mfma<false, false, false, true><<<gDD, 256, 0, stream>>>(hb, WvT + (size_t)L * MM, nullptr, nullptr, vb, DMODEL, DMODEL);
        attn_flash<<<dim3(TSEQ / 64, NHEADS, BATCH), 256, 0, stream>>>(qb, kb, vb, ob);
        gemm_mfma<false, false, true, false><<<gDD, 256, 0, stream>>>(ob, WoT + (size_t)L * MM, nullptr, x, x, DMODEL, DMODEL);
        ln_kernel<true><<<MROWS, 256, 0, stream>>>(x, ln2a + (size_t)L * DMODEL, ln2b + (size_t)L * DMODEL, hb);
        gemm_mfma<true, true, false, true><<<gDF, 256, 0, stream>>>(hb, W1T + (size_t)L * DFF * DMODEL, b1 + (size_t)L * DFF, nullptr, ff, DFF, DMODEL);
        gemm_mfma<true, false, true, false><<<gDD, 256, 0, stream>>>(ff, W2T + (size_t)L * DFF * DMODEL, b2 + (size_t)L * DMODEL, x, x, DMODEL, DFF);
    }

    if (pathA) {
        ln_kernel<true><<<MROWS, 256, 0, stream>>>(x, fa, fb, h2b);
        gemm_mfma<true, false, false, false><<<gDV, 256, 0, stream>>>(h2b, WpT, bp, nullptr, out, VOCAB, DMODEL);
    } else {
        ln_kernel<false><<<MROWS, 256, 0, stream>>>(x, fa, fb, hF);
        gemm_f32<<<dim3(VOCAB / BN, MROWS / BM), 256, 0, stream>>>(hF, Wp, bp, out, VOCAB, DMODEL);
    }
}

// Round 12
// 1914.099 us; speedup vs baseline: 8.0491x; 1.3004x over previous
//
#include <hip/hip_runtime.h>
#include <hip/hip_bf16.h>
#include <math.h>

#define VOCAB 32000
#define TSEQ 1024
#define DMODEL 1024
#define NLAYERS 6
#define NHEADS 16
#define DFF 4096
#define DKH 64
#define BATCH 2
#define MROWS (BATCH * TSEQ)   // 2048
#define LN_EPS 1e-6f
#define QKVS 3072              // fused qkv row stride

typedef unsigned short u16;
typedef __attribute__((ext_vector_type(8))) short short8v;
typedef __attribute__((ext_vector_type(4))) float f32x4;

__device__ __forceinline__ u16 f2bb(float f) {
    __hip_bfloat16 h = __float2bfloat16(f);
    u16 u; __builtin_memcpy(&u, &h, 2); return u;
}

__device__ __forceinline__ void gload16(const void* g, void* l) {
    __builtin_amdgcn_global_load_lds(
        (const __attribute__((address_space(1))) unsigned int*)g,
        (__attribute__((address_space(3))) unsigned int*)l, 16, 0, 0);
}

// ---------------- embedding + positional encoding ----------------
__global__ void embed_kernel(const int* __restrict__ idx,
                             const float* __restrict__ emb,
                             float* __restrict__ x) {
    int i = blockIdx.x * blockDim.x + threadIdx.x;
    if (i >= MROWS * DMODEL) return;
    int row = i / DMODEL;
    int d = i - row * DMODEL;
    int t = row % TSEQ;
    int tok = idx[row];
    float e = emb[(size_t)tok * DMODEL + d] * 32.0f;
    float freq = expf(-(float)(d & ~1) * (9.210340371976184f / (float)DMODEL));
    float ang = (float)t * freq;
    float pe = (d & 1) ? cosf(ang) : sinf(ang);
    x[i] = e + pe;
}

// ---------------- layernorm (ddof=1, denom = std + eps); bf16 or f32 out ----------------
template<bool OB16>
__global__ void __launch_bounds__(256) ln_kernel(const float* __restrict__ x,
                                                 const float* __restrict__ a,
                                                 const float* __restrict__ b,
                                                 void* __restrict__ yv) {
    __shared__ float red[8];
    int row = blockIdx.x;
    int tid = threadIdx.x;
    float4 v = ((const float4*)(x + (size_t)row * DMODEL))[tid];
    float s = v.x + v.y + v.z + v.w;
    #pragma unroll
    for (int off = 32; off; off >>= 1) s += __shfl_xor(s, off, 64);
    if ((tid & 63) == 0) red[tid >> 6] = s;
    __syncthreads();
    float mean = (red[0] + red[1] + red[2] + red[3]) * (1.0f / DMODEL);
    float dx = v.x - mean, dy = v.y - mean, dz = v.z - mean, dw = v.w - mean;
    float ss = dx * dx + dy * dy + dz * dz + dw * dw;
    #pragma unroll
    for (int off = 32; off; off >>= 1) ss += __shfl_xor(ss, off, 64);
    if ((tid & 63) == 0) red[4 + (tid >> 6)] = ss;
    __syncthreads();
    float var = (red[4] + red[5] + red[6] + red[7]) * (1.0f / (DMODEL - 1));
    float inv = 1.0f / (sqrtf(var) + LN_EPS);
    const float4 a4 = ((const float4*)a)[tid];
    const float4 b4 = ((const float4*)b)[tid];
    float o0 = a4.x * dx * inv + b4.x;
    float o1 = a4.y * dy * inv + b4.y;
    float o2 = a4.z * dz * inv + b4.z;
    float o3 = a4.w * dw * inv + b4.w;
    if (OB16) {
        ushort4 o; o.x = f2bb(o0); o.y = f2bb(o1); o.z = f2bb(o2); o.w = f2bb(o3);
        ((ushort4*)((u16*)yv + (size_t)row * DMODEL))[tid] = o;
    } else {
        float4 o; o.x = o0; o.y = o1; o.z = o2; o.w = o3;
        ((float4*)((float*)yv + (size_t)row * DMODEL))[tid] = o;
    }
}

// ---------------- transpose-convert: f32 [K,N] -> bf16 [N,K] ----------------
__global__ void __launch_bounds__(256) convT(const float* __restrict__ in,
                                             u16* __restrict__ out, int K, int N) {
    __shared__ float t[32][33];
    in  += (size_t)blockIdx.z * K * N;
    out += (size_t)blockIdx.z * K * N;
    const int tx = threadIdx.x, ty = threadIdx.y;
    const int n0 = blockIdx.x * 32, k0 = blockIdx.y * 32;
    #pragma unroll
    for (int i = 0; i < 4; ++i)
        t[ty + i * 8][tx] = in[(size_t)(k0 + ty + i * 8) * N + n0 + tx];
    __syncthreads();
    #pragma unroll
    for (int i = 0; i < 4; ++i)
        out[(size_t)(n0 + ty + i * 8) * K + k0 + tx] = f2bb(t[tx][ty + i * 8]);
}

// batched square-weight conversion: z = L*4+p, p in {q,k,v -> WqkvT} {o -> WoT}
__global__ void __launch_bounds__(256) convQKVO(const float* __restrict__ Wq,
                                                const float* __restrict__ Wk,
                                                const float* __restrict__ Wv,
                                                const float* __restrict__ Wo,
                                                u16* __restrict__ WqkvT,
                                                u16* __restrict__ WoT) {
    __shared__ float t[32][33];
    const int z = blockIdx.z, L = z >> 2, p = z & 3;
    const size_t MM = (size_t)DMODEL * DMODEL;
    const float* in = (p == 0 ? Wq : p == 1 ? Wk : p == 2 ? Wv : Wo) + (size_t)L * MM;
    u16* out = (p < 3) ? (WqkvT + (size_t)L * 3 * MM + (size_t)p * MM)
                       : (WoT + (size_t)L * MM);
    const int tx = threadIdx.x, ty = threadIdx.y;
    const int n0 = blockIdx.x * 32, k0 = blockIdx.y * 32;
    #pragma unroll
    for (int i = 0; i < 4; ++i)
        t[ty + i * 8][tx] = in[(size_t)(k0 + ty + i * 8) * DMODEL + n0 + tx];
    __syncthreads();
    #pragma unroll
    for (int i = 0; i < 4; ++i)
        out[(size_t)(n0 + ty + i * 8) * DMODEL + k0 + tx] = f2bb(t[tx][ty + i * 8]);
}

// ---------------- MFMA GEMM: C[M,N] = A_bf16[M,K] @ (Bt_bf16[N,K])^T + epilogue ----------------
// BMT x 128 tile, BK=32, 4 waves (2x2 quadrants of BMT/2 x 64). SWZ: XCD-chunked 1-D grid.
template<int BMT, bool BIAS, bool RELU, bool RES, bool OB16, bool SWZ>
__global__ void __launch_bounds__(256) gemm_mfma(
    const u16* __restrict__ A, const u16* __restrict__ Bt,
    const float* __restrict__ bias, const float* res,
    void* outp, int N, int K, int gm)
{
    constexpr int MR = BMT / 32;       // fragment rows per wave
    constexpr int AR = BMT / 64;       // A staging rounds
    __shared__ u16 Alds[BMT * 32];
    __shared__ u16 Blds[128 * 32];
    const int tid = threadIdx.x;
    const int w = tid >> 6, lane = tid & 63;
    const int wr = w >> 1, wc = w & 1;
    size_t bm, bn;
    if (SWZ) {
        const int bid = blockIdx.x, nwg = gridDim.x;
        const int q = nwg >> 3, r = nwg & 7;
        const int xc = bid & 7, sl = bid >> 3;
        const int wg = (xc < r ? xc * (q + 1) : r * (q + 1) + (xc - r) * q) + sl;
        bm = (size_t)(wg % gm) * BMT;
        bn = (size_t)(wg / gm) * 128;
    } else {
        bm = (size_t)blockIdx.y * BMT;
        bn = (size_t)blockIdx.x * 128;
    }
    const int srow = (w << 4) + (lane >> 2);
    const int scol = (lane & 3) << 3;
    const int fr = lane & 15, fq = lane >> 4;

    f32x4 acc[MR][4];
    #pragma unroll
    for (int m = 0; m < MR; ++m)
        #pragma unroll
        for (int n = 0; n < 4; ++n)
            acc[m][n] = (f32x4){0.f, 0.f, 0.f, 0.f};

    for (int k0 = 0; k0 < K; k0 += 32) {
        #pragma unroll
        for (int li = 0; li < AR; ++li)
            gload16(A + (bm + li * 64 + srow) * K + k0 + scol, Alds + li * 2048 + w * 512);
        #pragma unroll
        for (int li = 0; li < 2; ++li)
            gload16(Bt + (bn + li * 64 + srow) * K + k0 + scol, Blds + li * 2048 + w * 512);
        __syncthreads();
        short8v a[MR], b[4];
        #pragma unroll
        for (int m = 0; m < MR; ++m)
            a[m] = *(const short8v*)(Alds + (wr * (BMT / 2) + m * 16 + fr) * 32 + fq * 8);
        #pragma unroll
        for (int n = 0; n < 4; ++n)
            b[n] = *(const short8v*)(Blds + (wc * 64 + n * 16 + fr) * 32 + fq * 8);
        #pragma unroll
        for (int m = 0; m < MR; ++m)
            #pragma unroll
            for (int n = 0; n < 4; ++n)
                acc[m][n] = __builtin_amdgcn_mfma_f32_16x16x32_bf16(a[m], b[n], acc[m][n], 0, 0, 0);
        __syncthreads();
    }

    #pragma unroll
    for (int n = 0; n < 4; ++n) {
        const size_t col = bn + wc * 64 + n * 16 + fr;
        const float bv = BIAS ? bias[col] : 0.f;
        #pragma unroll
        for (int m = 0; m < MR; ++m) {
            #pragma unroll
            for (int r = 0; r < 4; ++r) {
                const size_t row = bm + wr * (BMT / 2) + m * 16 + fq * 4 + r;
                float v = acc[m][n][r] + bv;
                if (RELU) v = fmaxf(v, 0.f);
                if (RES)  v += res[row * N + col];
                if (OB16) ((u16*)outp)[row * N + col] = f2bb(v);
                else      ((float*)outp)[row * N + col] = v;
            }
        }
    }
}

// ---------------- flash attention over fused qkv [2048][3072] ----------------
__global__ void __launch_bounds__(256) attn_flash(const u16* __restrict__ qkv,
                                                  u16* __restrict__ o) {
    __shared__ u16 Klds[32 * 64];        // [kj][d], XOR-swizzled rows
    __shared__ u16 Vt[64 * 32];          // [d][kj], chunk-rotated
    __shared__ u16 Plds[4][16 * 40];

    const int tid = threadIdx.x;
    const int w = tid >> 6, lane = tid & 63;
    const int fr = lane & 15, fq = lane >> 4;
    const int qt = blockIdx.x, h = blockIdx.y, b = blockIdx.z;
    const int qbase = qt * 64 + w * 16;
    const size_t rowbase = (size_t)b * TSEQ;
    const int hd = h * DKH;

    const u16* qrow = qkv + (rowbase + qbase + fr) * QKVS + hd;
    const short8v qf0 = *(const short8v*)(qrow + fq * 8);
    const short8v qf1 = *(const short8v*)(qrow + 32 + fq * 8);

    float m[4], l[4];
    f32x4 oa[4];
    #pragma unroll
    for (int r = 0; r < 4; ++r) { m[r] = -1e30f; l[r] = 0.f; }
    #pragma unroll
    for (int nd = 0; nd < 4; ++nd) oa[nd] = (f32x4){0.f, 0.f, 0.f, 0.f};

    const int ntiles = qt * 2 + 2;
    for (int t = 0; t < ntiles; ++t) {
        const int j0 = t * 32;
        {
            const int r = tid >> 3, c8 = (tid & 7) << 3;
            const size_t grow = (rowbase + j0 + r) * QKVS + hd + c8;
            short8v kv = *(const short8v*)(qkv + grow + 1024);
            int kbyte = (r * 128 + c8 * 2) ^ ((r & 7) << 4);
            *(short8v*)((char*)Klds + kbyte) = kv;
            short8v vv = *(const short8v*)(qkv + grow + 2048);
            #pragma unroll
            for (int i = 0; i < 8; ++i) {
                const int vrow = c8 + i;               // d index
                const int chunk = ((r >> 3) + (vrow >> 3)) & 3;
                Vt[vrow * 32 + chunk * 8 + (r & 7)] = (u16)vv[i];
            }
        }
        __syncthreads();

        if (j0 <= qbase + 15) {
            f32x4 s[2];
            #pragma unroll
            for (int ct = 0; ct < 2; ++ct) {
                const int krow = ct * 16 + fr;
                const int swz = (krow & 7) << 4;
                short8v k0 = *(const short8v*)((char*)Klds + ((krow * 128 + fq * 16) ^ swz));
                short8v k1 = *(const short8v*)((char*)Klds + ((krow * 128 + 64 + fq * 16) ^ swz));
                f32x4 a = (f32x4){0.f, 0.f, 0.f, 0.f};
                a = __builtin_amdgcn_mfma_f32_16x16x32_bf16(qf0, k0, a, 0, 0, 0);
                a = __builtin_amdgcn_mfma_f32_16x16x32_bf16(qf1, k1, a, 0, 0, 0);
                s[ct] = a;
            }
            float c[4];
            #pragma unroll
            for (int r = 0; r < 4; ++r) {
                const int qg = qbase + fq * 4 + r;
                float s0 = s[0][r] * 0.125f;
                float s1 = s[1][r] * 0.125f;
                if (j0 + fr      > qg) s0 = -1e30f;
                if (j0 + 16 + fr > qg) s1 = -1e30f;
                float mx = fmaxf(s0, s1);
                mx = fmaxf(mx, __shfl_xor(mx, 1, 64));
                mx = fmaxf(mx, __shfl_xor(mx, 2, 64));
                mx = fmaxf(mx, __shfl_xor(mx, 4, 64));
                mx = fmaxf(mx, __shfl_xor(mx, 8, 64));
                const float mn = fmaxf(m[r], mx);
                c[r] = __expf(m[r] - mn);
                m[r] = mn;
                const float p0 = __expf(s0 - mn);
                const float p1 = __expf(s1 - mn);
                float rs = p0 + p1;
                rs += __shfl_xor(rs, 1, 64);
                rs += __shfl_xor(rs, 2, 64);
                rs += __shfl_xor(rs, 4, 64);
                rs += __shfl_xor(rs, 8, 64);
                l[r] = l[r] * c[r] + rs;
                Plds[w][(fq * 4 + r) * 40 + fr]      = f2bb(p0);
                Plds[w][(fq * 4 + r) * 40 + 16 + fr] = f2bb(p1);
            }
            #pragma unroll
            for (int nd = 0; nd < 4; ++nd)
                #pragma unroll
                for (int r = 0; r < 4; ++r)
                    oa[nd][r] *= c[r];
            asm volatile("s_waitcnt lgkmcnt(0)" ::: "memory");
            __builtin_amdgcn_sched_barrier(0);
            const short8v pf = *(const short8v*)(&Plds[w][fr * 40 + fq * 8]);
            #pragma unroll
            for (int nd = 0; nd < 4; ++nd) {
                const int vrow = nd * 16 + fr;
                const int chunk = (fq + (vrow >> 3)) & 3;
                const short8v vf = *(const short8v*)(&Vt[vrow * 32 + chunk * 8]);
                oa[nd] = __builtin_amdgcn_mfma_f32_16x16x32_bf16(pf, vf, oa[nd], 0, 0, 0);
            }
        }
        __syncthreads();
    }

    #pragma unroll
    for (int r = 0; r < 4; ++r) {
        const float inv = 1.0f / l[r];
        u16* orow = o + (rowbase + qbase + fq * 4 + r) * DMODEL + hd;
        #pragma unroll
        for (int nd = 0; nd < 4; ++nd)
            orow[nd * 16 + fr] = f2bb(oa[nd][r] * inv);
    }
}

// ---------------- f32 GEMM (fallback vocab path only) ----------------
#define FBM 64
#define FBN 64
#define FBK 16
__global__ void __launch_bounds__(256) gemm_f32(
    const float* __restrict__ A, const float* __restrict__ Bw,
    const float* __restrict__ bias, float* outp, int N, int K)
{
    __shared__ float As[FBK][FBM];
    __shared__ float Bs[FBK][FBN];
    const int bm = blockIdx.y * FBM, bn = blockIdx.x * FBN;
    const int tid = threadIdx.x;
    const int tr = (tid >> 4) << 2, tc = (tid & 15) << 2;
    const int am = tid >> 2, ak = (tid & 3) << 2;
    const int bk = tid >> 4, bn4 = (tid & 15) << 2;
    float acc[4][4] = {};
    const float* Ap = A + (size_t)(bm + am) * K + ak;
    const float* Bp = Bw + (size_t)bk * N + bn + bn4;
    for (int k0 = 0; k0 < K; k0 += FBK) {
        float4 av = *(const float4*)(Ap + k0);
        float4 bv = *(const float4*)(Bp + (size_t)k0 * N);
        As[ak + 0][am] = av.x; As[ak + 1][am] = av.y; As[ak + 2][am] = av.z; As[ak + 3][am] = av.w;
        *(float4*)&Bs[bk][bn4] = bv;
        __syncthreads();
        #pragma unroll
        for (int kk = 0; kk < FBK; ++kk) {
            float4 a4 = *(const float4*)&As[kk][tr];
            float4 b4 = *(const float4*)&Bs[kk][tc];
            acc[0][0] += a4.x*b4.x; acc[0][1] += a4.x*b4.y; acc[0][2] += a4.x*b4.z; acc[0][3] += a4.x*b4.w;
            acc[1][0] += a4.y*b4.x; acc[1][1] += a4.y*b4.y; acc[1][2] += a4.y*b4.z; acc[1][3] += a4.y*b4.w;
            acc[2][0] += a4.z*b4.x; acc[2][1] += a4.z*b4.y; acc[2][2] += a4.z*b4.z; acc[2][3] += a4.z*b4.w;
            acc[3][0] += a4.w*b4.x; acc[3][1] += a4.w*b4.y; acc[3][2] += a4.w*b4.z; acc[3][3] += a4.w*b4.w;
        }
        __syncthreads();
    }
    #pragma unroll
    for (int i = 0; i < 4; ++i) {
        int row = bm + tr + i;
        float4 o;
        o.x = acc[i][0] + bias[bn + tc + 0];
        o.y = acc[i][1] + bias[bn + tc + 1];
        o.z = acc[i][2] + bias[bn + tc + 2];
        o.w = acc[i][3] + bias[bn + tc + 3];
        *(float4*)(outp + (size_t)row * N + bn + tc) = o;
    }
}

// ---------------- host ----------------
extern "C" void kernel_launch(void* const* d_in, const int* in_sizes, int n_in,
                              void* d_out, int out_size, void* d_ws, size_t ws_size,
                              hipStream_t stream) {
    const int* idx = (const int*)d_in[0];
    const float* emb = (const float*)d_in[1];
    const float* Wq = (const float*)d_in[2];
    const float* Wk = (const float*)d_in[3];
    const float* Wv = (const float*)d_in[4];
    const float* Wo = (const float*)d_in[5];
    const float* ln1a = (const float*)d_in[6];
    const float* ln1b = (const float*)d_in[7];
    const float* ln2a = (const float*)d_in[8];
    const float* ln2b = (const float*)d_in[9];
    const float* W1 = (const float*)d_in[10];
    const float* b1 = (const float*)d_in[11];
    const float* W2 = (const float*)d_in[12];
    const float* b2 = (const float*)d_in[13];
    const float* fa = (const float*)d_in[14];
    const float* fb = (const float*)d_in[15];
    const float* Wp = (const float*)d_in[16];
    const float* bp = (const float*)d_in[17];
    float* out = (float*)d_out;

    // ---- d_out-as-scratch, u16 units (MD = 2M u16, MM = 1M u16) ----
    // [0,3MD) qkv | [3MD,4MD) ob | [4MD,5MD) hb | [5MD,7MD) x f32 | [7MD,11MD) ff
    // [12MD,21MD) WqkvT | [21MD,24MD) WoT | [24MD,36MD) W1T | [36MD,48MD) W2T
    const size_t MD = (size_t)MROWS * DMODEL;
    const size_t MM = (size_t)DMODEL * DMODEL;
    u16* U = (u16*)out;
    u16* qkv = U;
    u16* ob = U + 3 * MD;
    u16* hb = U + 4 * MD;
    float* x = (float*)(U + 5 * MD);
    u16* ff = U + 7 * MD;
    u16* WqkvT = U + 12 * MD;
    u16* WoT = U + 21 * MD;
    u16* W1T = U + 24 * MD;
    u16* W2T = U + 36 * MD;

    const bool pathA = ws_size >= (size_t)68 * 1024 * 1024 + 256;
    u16* WpT = (u16*)d_ws;
    u16* h2b = (u16*)((char*)d_ws + (size_t)64 * 1024 * 1024);
    float* hF = (float*)d_ws;

    dim3 cblk(32, 8);
    convQKVO<<<dim3(32, 32, 24), cblk, 0, stream>>>(Wq, Wk, Wv, Wo, WqkvT, WoT);
    convT<<<dim3(128, 32, 6), cblk, 0, stream>>>(W1, W1T, DMODEL, DFF);
    convT<<<dim3(32, 128, 6), cblk, 0, stream>>>(W2, W2T, DFF, DMODEL);
    if (pathA) convT<<<dim3(1000, 32, 1), cblk, 0, stream>>>(Wp, WpT, DMODEL, VOCAB);

    embed_kernel<<<(MROWS * DMODEL + 255) / 256, 256, 0, stream>>>(idx, emb, x);

    for (int L = 0; L < NLAYERS; ++L) {
        ln_kernel<true><<<MROWS, 256, 0, stream>>>(x, ln1a + (size_t)L * DMODEL, ln1b + (size_t)L * DMODEL, hb);
        // fused qkv = h @ [Wq|Wk|Wv]  (N=3072, 24x16 = 384 blocks)
        gemm_mfma<128, false, false, false, true, false><<<dim3(24, 16), 256, 0, stream>>>(
            hb, WqkvT + (size_t)L * 3 * MM, nullptr, nullptr, qkv, QKVS, DMODEL, 0);
        attn_flash<<<dim3(TSEQ / 64, NHEADS, BATCH), 256, 0, stream>>>(qkv, ob);
        // x += ob @ Wo  (BM=64: 8x32 = 256 blocks)
        gemm_mfma<64, false, false, true, false, false><<<dim3(8, 32), 256, 0, stream>>>(
            ob, WoT + (size_t)L * MM, nullptr, x, x, DMODEL, DMODEL, 0);
        ln_kernel<true><<<MROWS, 256, 0, stream>>>(x, ln2a + (size_t)L * DMODEL, ln2b + (size_t)L * DMODEL, hb);
        // ff = relu(h @ W1 + b1)  (32x16 = 512 blocks)
        gemm_mfma<128, true, true, false, true, false><<<dim3(32, 16), 256, 0, stream>>>(
            hb, W1T + (size_t)L * DFF * DMODEL, b1 + (size_t)L * DFF, nullptr, ff, DFF, DMODEL, 0);
        // x += ff @ W2 + b2  (BM=64: 8x32 = 256 blocks)
        gemm_mfma<64, true, false, true, false, false><<<dim3(8, 32), 256, 0, stream>>>(
            ff, W2T + (size_t)L * DFF * DMODEL, b2 + (size_t)L * DMODEL, x, x, DMODEL, DFF, 0);
    }

    if (pathA) {
        ln_kernel<true><<<MROWS, 256, 0, stream>>>(x, fa, fb, h2b);
        // vocab: 1-D grid 4000, XCD-chunked, M-major within chunk (gm=16)
        gemm_mfma<128, true, false, false, false, true><<<dim3(4000), 256, 0, stream>>>(
            h2b, WpT, bp, nullptr, out, VOCAB, DMODEL, MROWS / 128);
    } else {
        ln_kernel<false><<<MROWS, 256, 0, stream>>>(x, fa, fb, hF);
        gemm_f32<<<dim3(VOCAB / FBN, MROWS / FBM), 256, 0, stream>>>(hF, Wp, bp, out, VOCAB, DMODEL);
    }
}

// Round 13
// 1840.182 us; speedup vs baseline: 8.3725x; 1.0402x over previous
//
#include <hip/hip_runtime.h>
#include <hip/hip_bf16.h>
#include <math.h>

#define VOCAB 32000
#define TSEQ 1024
#define DMODEL 1024
#define NLAYERS 6
#define NHEADS 16
#define DFF 4096
#define DKH 64
#define BATCH 2
#define MROWS (BATCH * TSEQ)   // 2048
#define LN_EPS 1e-6f
#define QKVS 3072              // fused qkv row stride

typedef unsigned short u16;
typedef __attribute__((ext_vector_type(8))) short short8v;
typedef __attribute__((ext_vector_type(4))) float f32x4;

__device__ __forceinline__ u16 f2bb(float f) {
    __hip_bfloat16 h = __float2bfloat16(f);
    u16 u; __builtin_memcpy(&u, &h, 2); return u;
}

__device__ __forceinline__ void gload16(const void* g, void* l) {
    __builtin_amdgcn_global_load_lds(
        (const __attribute__((address_space(1))) unsigned int*)g,
        (__attribute__((address_space(3))) unsigned int*)l, 16, 0, 0);
}

// ---------------- embedding + positional encoding ----------------
__global__ void embed_kernel(const int* __restrict__ idx,
                             const float* __restrict__ emb,
                             float* __restrict__ x) {
    int i = blockIdx.x * blockDim.x + threadIdx.x;
    if (i >= MROWS * DMODEL) return;
    int row = i / DMODEL;
    int d = i - row * DMODEL;
    int t = row % TSEQ;
    int tok = idx[row];
    float e = emb[(size_t)tok * DMODEL + d] * 32.0f;
    float freq = expf(-(float)(d & ~1) * (9.210340371976184f / (float)DMODEL));
    float ang = (float)t * freq;
    float pe = (d & 1) ? cosf(ang) : sinf(ang);
    x[i] = e + pe;
}

// ---------------- layernorm (ddof=1, denom = std + eps); bf16 or f32 out ----------------
template<bool OB16>
__global__ void __launch_bounds__(256) ln_kernel(const float* __restrict__ x,
                                                 const float* __restrict__ a,
                                                 const float* __restrict__ b,
                                                 void* __restrict__ yv) {
    __shared__ float red[8];
    int row = blockIdx.x;
    int tid = threadIdx.x;
    float4 v = ((const float4*)(x + (size_t)row * DMODEL))[tid];
    float s = v.x + v.y + v.z + v.w;
    #pragma unroll
    for (int off = 32; off; off >>= 1) s += __shfl_xor(s, off, 64);
    if ((tid & 63) == 0) red[tid >> 6] = s;
    __syncthreads();
    float mean = (red[0] + red[1] + red[2] + red[3]) * (1.0f / DMODEL);
    float dx = v.x - mean, dy = v.y - mean, dz = v.z - mean, dw = v.w - mean;
    float ss = dx * dx + dy * dy + dz * dz + dw * dw;
    #pragma unroll
    for (int off = 32; off; off >>= 1) ss += __shfl_xor(ss, off, 64);
    if ((tid & 63) == 0) red[4 + (tid >> 6)] = ss;
    __syncthreads();
    float var = (red[4] + red[5] + red[6] + red[7]) * (1.0f / (DMODEL - 1));
    float inv = 1.0f / (sqrtf(var) + LN_EPS);
    const float4 a4 = ((const float4*)a)[tid];
    const float4 b4 = ((const float4*)b)[tid];
    float o0 = a4.x * dx * inv + b4.x;
    float o1 = a4.y * dy * inv + b4.y;
    float o2 = a4.z * dz * inv + b4.z;
    float o3 = a4.w * dw * inv + b4.w;
    if (OB16) {
        ushort4 o; o.x = f2bb(o0); o.y = f2bb(o1); o.z = f2bb(o2); o.w = f2bb(o3);
        ((ushort4*)((u16*)yv + (size_t)row * DMODEL))[tid] = o;
    } else {
        float4 o; o.x = o0; o.y = o1; o.z = o2; o.w = o3;
        ((float4*)((float*)yv + (size_t)row * DMODEL))[tid] = o;
    }
}

// ---------------- transpose-convert: f32 [K,N] -> bf16 [N,K] ----------------
__global__ void __launch_bounds__(256) convT(const float* __restrict__ in,
                                             u16* __restrict__ out, int K, int N) {
    __shared__ float t[32][33];
    in  += (size_t)blockIdx.z * K * N;
    out += (size_t)blockIdx.z * K * N;
    const int tx = threadIdx.x, ty = threadIdx.y;
    const int n0 = blockIdx.x * 32, k0 = blockIdx.y * 32;
    #pragma unroll
    for (int i = 0; i < 4; ++i)
        t[ty + i * 8][tx] = in[(size_t)(k0 + ty + i * 8) * N + n0 + tx];
    __syncthreads();
    #pragma unroll
    for (int i = 0; i < 4; ++i)
        out[(size_t)(n0 + ty + i * 8) * K + k0 + tx] = f2bb(t[tx][ty + i * 8]);
}

// batched square-weight conversion: z = L*4+p, p in {q,k,v -> WqkvT} {o -> WoT}
__global__ void __launch_bounds__(256) convQKVO(const float* __restrict__ Wq,
                                                const float* __restrict__ Wk,
                                                const float* __restrict__ Wv,
                                                const float* __restrict__ Wo,
                                                u16* __restrict__ WqkvT,
                                                u16* __restrict__ WoT) {
    __shared__ float t[32][33];
    const int z = blockIdx.z, L = z >> 2, p = z & 3;
    const size_t MM = (size_t)DMODEL * DMODEL;
    const float* in = (p == 0 ? Wq : p == 1 ? Wk : p == 2 ? Wv : Wo) + (size_t)L * MM;
    u16* out = (p < 3) ? (WqkvT + (size_t)L * 3 * MM + (size_t)p * MM)
                       : (WoT + (size_t)L * MM);
    const int tx = threadIdx.x, ty = threadIdx.y;
    const int n0 = blockIdx.x * 32, k0 = blockIdx.y * 32;
    #pragma unroll
    for (int i = 0; i < 4; ++i)
        t[ty + i * 8][tx] = in[(size_t)(k0 + ty + i * 8) * DMODEL + n0 + tx];
    __syncthreads();
    #pragma unroll
    for (int i = 0; i < 4; ++i)
        out[(size_t)(n0 + ty + i * 8) * DMODEL + k0 + tx] = f2bb(t[tx][ty + i * 8]);
}

// ---------------- MFMA GEMM: C[M,N] = A_bf16[M,K] @ (Bt_bf16[N,K])^T + epilogue ----------------
// BMT x 128 tile, BK=32, 4 waves (2x2 quadrants). LDS rows 64B; 16B blocks XOR-swizzled
// (pre-swizzled GLOBAL source + swizzled read; global_load_lds dest stays linear, rule #21).
template<int BMT, bool BIAS, bool RELU, bool RES, bool OB16>
__global__ void __launch_bounds__(256) gemm_mfma(
    const u16* __restrict__ A, const u16* __restrict__ Bt,
    const float* __restrict__ bias, const float* res,
    void* outp, int N, int K)
{
    constexpr int MR = BMT / 32;       // fragment rows per wave
    constexpr int AR = BMT / 64;       // A staging rounds
    __shared__ u16 Alds[BMT * 32];
    __shared__ u16 Blds[128 * 32];
    const int tid = threadIdx.x;
    const int w = tid >> 6, lane = tid & 63;
    const int wr = w >> 1, wc = w & 1;
    const size_t bm = (size_t)blockIdx.y * BMT;
    const size_t bn = (size_t)blockIdx.x * 128;
    const int srow = (w << 4) + (lane >> 2);
    const int scol = (((lane & 3) ^ ((lane >> 3) & 3)) << 3);   // pre-swizzled source block
    const int fr = lane & 15, fq = lane >> 4;
    const int aswz = ((fq ^ ((fr >> 1) & 3)) << 3);             // swizzled read block

    f32x4 acc[MR][4];
    #pragma unroll
    for (int m = 0; m < MR; ++m)
        #pragma unroll
        for (int n = 0; n < 4; ++n)
            acc[m][n] = (f32x4){0.f, 0.f, 0.f, 0.f};

    for (int k0 = 0; k0 < K; k0 += 32) {
        #pragma unroll
        for (int li = 0; li < AR; ++li)
            gload16(A + (bm + li * 64 + srow) * K + k0 + scol, Alds + li * 2048 + w * 512);
        #pragma unroll
        for (int li = 0; li < 2; ++li)
            gload16(Bt + (bn + li * 64 + srow) * K + k0 + scol, Blds + li * 2048 + w * 512);
        __syncthreads();
        short8v a[MR], b[4];
        #pragma unroll
        for (int m = 0; m < MR; ++m)
            a[m] = *(const short8v*)(Alds + (wr * (BMT / 2) + m * 16 + fr) * 32 + aswz);
        #pragma unroll
        for (int n = 0; n < 4; ++n)
            b[n] = *(const short8v*)(Blds + (wc * 64 + n * 16 + fr) * 32 + aswz);
        #pragma unroll
        for (int m = 0; m < MR; ++m)
            #pragma unroll
            for (int n = 0; n < 4; ++n)
                acc[m][n] = __builtin_amdgcn_mfma_f32_16x16x32_bf16(a[m], b[n], acc[m][n], 0, 0, 0);
        __syncthreads();
    }

    #pragma unroll
    for (int n = 0; n < 4; ++n) {
        const size_t col = bn + wc * 64 + n * 16 + fr;
        const float bv = BIAS ? bias[col] : 0.f;
        #pragma unroll
        for (int m = 0; m < MR; ++m) {
            #pragma unroll
            for (int r = 0; r < 4; ++r) {
                const size_t row = bm + wr * (BMT / 2) + m * 16 + fq * 4 + r;
                float v = acc[m][n][r] + bv;
                if (RELU) v = fmaxf(v, 0.f);
                if (RES)  v += res[row * N + col];
                if (OB16) ((u16*)outp)[row * N + col] = f2bb(v);
                else      ((float*)outp)[row * N + col] = v;
            }
        }
    }
}

// ---------------- flash attention over fused qkv [2048][3072] ----------------
__global__ void __launch_bounds__(256) attn_flash(const u16* __restrict__ qkv,
                                                  u16* __restrict__ o) {
    __shared__ u16 Klds[32 * 64];        // [kj][d], XOR-swizzled rows
    __shared__ u16 Vt[64 * 32];          // [d][kj], chunk-rotated
    __shared__ u16 Plds[4][16 * 40];

    const int tid = threadIdx.x;
    const int w = tid >> 6, lane = tid & 63;
    const int fr = lane & 15, fq = lane >> 4;
    const int qt = blockIdx.x, h = blockIdx.y, b = blockIdx.z;
    const int qbase = qt * 64 + w * 16;
    const size_t rowbase = (size_t)b * TSEQ;
    const int hd = h * DKH;

    const u16* qrow = qkv + (rowbase + qbase + fr) * QKVS + hd;
    const short8v qf0 = *(const short8v*)(qrow + fq * 8);
    const short8v qf1 = *(const short8v*)(qrow + 32 + fq * 8);

    float m[4], l[4];
    f32x4 oa[4];
    #pragma unroll
    for (int r = 0; r < 4; ++r) { m[r] = -1e30f; l[r] = 0.f; }
    #pragma unroll
    for (int nd = 0; nd < 4; ++nd) oa[nd] = (f32x4){0.f, 0.f, 0.f, 0.f};

    const int ntiles = qt * 2 + 2;
    for (int t = 0; t < ntiles; ++t) {
        const int j0 = t * 32;
        {
            const int r = tid >> 3, c8 = (tid & 7) << 3;
            const size_t grow = (rowbase + j0 + r) * QKVS + hd + c8;
            short8v kv = *(const short8v*)(qkv + grow + 1024);
            int kbyte = (r * 128 + c8 * 2) ^ ((r & 7) << 4);
            *(short8v*)((char*)Klds + kbyte) = kv;
            short8v vv = *(const short8v*)(qkv + grow + 2048);
            #pragma unroll
            for (int i = 0; i < 8; ++i) {
                const int vrow = c8 + i;
                const int chunk = ((r >> 3) + (vrow >> 3)) & 3;
                Vt[vrow * 32 + chunk * 8 + (r & 7)] = (u16)vv[i];
            }
        }
        __syncthreads();

        if (j0 <= qbase + 15) {
            f32x4 s[2];
            #pragma unroll
            for (int ct = 0; ct < 2; ++ct) {
                const int krow = ct * 16 + fr;
                const int swz = (krow & 7) << 4;
                short8v k0 = *(const short8v*)((char*)Klds + ((krow * 128 + fq * 16) ^ swz));
                short8v k1 = *(const short8v*)((char*)Klds + ((krow * 128 + 64 + fq * 16) ^ swz));
                f32x4 a = (f32x4){0.f, 0.f, 0.f, 0.f};
                a = __builtin_amdgcn_mfma_f32_16x16x32_bf16(qf0, k0, a, 0, 0, 0);
                a = __builtin_amdgcn_mfma_f32_16x16x32_bf16(qf1, k1, a, 0, 0, 0);
                s[ct] = a;
            }
            float c[4];
            #pragma unroll
            for (int r = 0; r < 4; ++r) {
                const int qg = qbase + fq * 4 + r;
                float s0 = s[0][r] * 0.125f;
                float s1 = s[1][r] * 0.125f;
                if (j0 + fr      > qg) s0 = -1e30f;
                if (j0 + 16 + fr > qg) s1 = -1e30f;
                float mx = fmaxf(s0, s1);
                mx = fmaxf(mx, __shfl_xor(mx, 1, 64));
                mx = fmaxf(mx, __shfl_xor(mx, 2, 64));
                mx = fmaxf(mx, __shfl_xor(mx, 4, 64));
                mx = fmaxf(mx, __shfl_xor(mx, 8, 64));
                const float mn = fmaxf(m[r], mx);
                c[r] = __expf(m[r] - mn);
                m[r] = mn;
                const float p0 = __expf(s0 - mn);
                const float p1 = __expf(s1 - mn);
                float rs = p0 + p1;
                rs += __shfl_xor(rs, 1, 64);
                rs += __shfl_xor(rs, 2, 64);
                rs += __shfl_xor(rs, 4, 64);
                rs += __shfl_xor(rs, 8, 64);
                l[r] = l[r] * c[r] + rs;
                Plds[w][(fq * 4 + r) * 40 + fr]      = f2bb(p0);
                Plds[w][(fq * 4 + r) * 40 + 16 + fr] = f2bb(p1);
            }
            #pragma unroll
            for (int nd = 0; nd < 4; ++nd)
                #pragma unroll
                for (int r = 0; r < 4; ++r)
                    oa[nd][r] *= c[r];
            asm volatile("s_waitcnt lgkmcnt(0)" ::: "memory");
            __builtin_amdgcn_sched_barrier(0);
            const short8v pf = *(const short8v*)(&Plds[w][fr * 40 + fq * 8]);
            #pragma unroll
            for (int nd = 0; nd < 4; ++nd) {
                const int vrow = nd * 16 + fr;
                const int chunk = (fq + (vrow >> 3)) & 3;
                const short8v vf = *(const short8v*)(&Vt[vrow * 32 + chunk * 8]);
                oa[nd] = __builtin_amdgcn_mfma_f32_16x16x32_bf16(pf, vf, oa[nd], 0, 0, 0);
            }
        }
        __syncthreads();
    }

    #pragma unroll
    for (int r = 0; r < 4; ++r) {
        const float inv = 1.0f / l[r];
        u16* orow = o + (rowbase + qbase + fq * 4 + r) * DMODEL + hd;
        #pragma unroll
        for (int nd = 0; nd < 4; ++nd)
            orow[nd * 16 + fr] = f2bb(oa[nd][r] * inv);
    }
}

// ---------------- f32 GEMM (fallback vocab path only) ----------------
#define FBM 64
#define FBN 64
#define FBK 16
__global__ void __launch_bounds__(256) gemm_f32(
    const float* __restrict__ A, const float* __restrict__ Bw,
    const float* __restrict__ bias, float* outp, int N, int K)
{
    __shared__ float As[FBK][FBM];
    __shared__ float Bs[FBK][FBN];
    const int bm = blockIdx.y * FBM, bn = blockIdx.x * FBN;
    const int tid = threadIdx.x;
    const int tr = (tid >> 4) << 2, tc = (tid & 15) << 2;
    const int am = tid >> 2, ak = (tid & 3) << 2;
    const int bk = tid >> 4, bn4 = (tid & 15) << 2;
    float acc[4][4] = {};
    const float* Ap = A + (size_t)(bm + am) * K + ak;
    const float* Bp = Bw + (size_t)bk * N + bn + bn4;
    for (int k0 = 0; k0 < K; k0 += FBK) {
        float4 av = *(const float4*)(Ap + k0);
        float4 bv = *(const float4*)(Bp + (size_t)k0 * N);
        As[ak + 0][am] = av.x; As[ak + 1][am] = av.y; As[ak + 2][am] = av.z; As[ak + 3][am] = av.w;
        *(float4*)&Bs[bk][bn4] = bv;
        __syncthreads();
        #pragma unroll
        for (int kk = 0; kk < FBK; ++kk) {
            float4 a4 = *(const float4*)&As[kk][tr];
            float4 b4 = *(const float4*)&Bs[kk][tc];
            acc[0][0] += a4.x*b4.x; acc[0][1] += a4.x*b4.y; acc[0][2] += a4.x*b4.z; acc[0][3] += a4.x*b4.w;
            acc[1][0] += a4.y*b4.x; acc[1][1] += a4.y*b4.y; acc[1][2] += a4.y*b4.z; acc[1][3] += a4.y*b4.w;
            acc[2][0] += a4.z*b4.x; acc[2][1] += a4.z*b4.y; acc[2][2] += a4.z*b4.z; acc[2][3] += a4.z*b4.w;
            acc[3][0] += a4.w*b4.x; acc[3][1] += a4.w*b4.y; acc[3][2] += a4.w*b4.z; acc[3][3] += a4.w*b4.w;
        }
        __syncthreads();
    }
    #pragma unroll
    for (int i = 0; i < 4; ++i) {
        int row = bm + tr + i;
        float4 o;
        o.x = acc[i][0] + bias[bn + tc + 0];
        o.y = acc[i][1] + bias[bn + tc + 1];
        o.z = acc[i][2] + bias[bn + tc + 2];
        o.w = acc[i][3] + bias[bn + tc + 3];
        *(float4*)(outp + (size_t)row * N + bn + tc) = o;
    }
}

// ---------------- host ----------------
extern "C" void kernel_launch(void* const* d_in, const int* in_sizes, int n_in,
                              void* d_out, int out_size, void* d_ws, size_t ws_size,
                              hipStream_t stream) {
    const int* idx = (const int*)d_in[0];
    const float* emb = (const float*)d_in[1];
    const float* Wq = (const float*)d_in[2];
    const float* Wk = (const float*)d_in[3];
    const float* Wv = (const float*)d_in[4];
    const float* Wo = (const float*)d_in[5];
    const float* ln1a = (const float*)d_in[6];
    const float* ln1b = (const float*)d_in[7];
    const float* ln2a = (const float*)d_in[8];
    const float* ln2b = (const float*)d_in[9];
    const float* W1 = (const float*)d_in[10];
    const float* b1 = (const float*)d_in[11];
    const float* W2 = (const float*)d_in[12];
    const float* b2 = (const float*)d_in[13];
    const float* fa = (const float*)d_in[14];
    const float* fb = (const float*)d_in[15];
    const float* Wp = (const float*)d_in[16];
    const float* bp = (const float*)d_in[17];
    float* out = (float*)d_out;

    const size_t MD = (size_t)MROWS * DMODEL;
    const size_t MM = (size_t)DMODEL * DMODEL;
    u16* U = (u16*)out;
    u16* qkv = U;
    u16* ob = U + 3 * MD;
    u16* hb = U + 4 * MD;
    float* x = (float*)(U + 5 * MD);
    u16* ff = U + 7 * MD;
    u16* WqkvT = U + 12 * MD;
    u16* WoT = U + 21 * MD;
    u16* W1T = U + 24 * MD;
    u16* W2T = U + 36 * MD;

    const bool pathA = ws_size >= (size_t)68 * 1024 * 1024 + 256;
    u16* WpT = (u16*)d_ws;
    u16* h2b = (u16*)((char*)d_ws + (size_t)64 * 1024 * 1024);
    float* hF = (float*)d_ws;

    dim3 cblk(32, 8);
    convQKVO<<<dim3(32, 32, 24), cblk, 0, stream>>>(Wq, Wk, Wv, Wo, WqkvT, WoT);
    convT<<<dim3(128, 32, 6), cblk, 0, stream>>>(W1, W1T, DMODEL, DFF);
    convT<<<dim3(32, 128, 6), cblk, 0, stream>>>(W2, W2T, DFF, DMODEL);
    if (pathA) convT<<<dim3(1000, 32, 1), cblk, 0, stream>>>(Wp, WpT, DMODEL, VOCAB);

    embed_kernel<<<(MROWS * DMODEL + 255) / 256, 256, 0, stream>>>(idx, emb, x);

    for (int L = 0; L < NLAYERS; ++L) {
        ln_kernel<true><<<MROWS, 256, 0, stream>>>(x, ln1a + (size_t)L * DMODEL, ln1b + (size_t)L * DMODEL, hb);
        gemm_mfma<128, false, false, false, true><<<dim3(24, 16), 256, 0, stream>>>(
            hb, WqkvT + (size_t)L * 3 * MM, nullptr, nullptr, qkv, QKVS, DMODEL);
        attn_flash<<<dim3(TSEQ / 64, NHEADS, BATCH), 256, 0, stream>>>(qkv, ob);
        gemm_mfma<64, false, false, true, false><<<dim3(8, 32), 256, 0, stream>>>(
            ob, WoT + (size_t)L * MM, nullptr, x, x, DMODEL, DMODEL);
        ln_kernel<true><<<MROWS, 256, 0, stream>>>(x, ln2a + (size_t)L * DMODEL, ln2b + (size_t)L * DMODEL, hb);
        gemm_mfma<128, true, true, false, true><<<dim3(32, 16), 256, 0, stream>>>(
            hb, W1T + (size_t)L * DFF * DMODEL, b1 + (size_t)L * DFF, nullptr, ff, DFF, DMODEL);
        gemm_mfma<64, true, false, true, false><<<dim3(8, 32), 256, 0, stream>>>(
            ff, W2T + (size_t)L * DFF * DMODEL, b2 + (size_t)L * DMODEL, x, x, DMODEL, DFF);
    }

    if (pathA) {
        ln_kernel<true><<<MROWS, 256, 0, stream>>>(x, fa, fb, h2b);
        // vocab: 2-D grid, N-fastest (row-contiguous C writes)
        gemm_mfma<128, true, false, false, false><<<dim3(250, 16), 256, 0, stream>>>(
            h2b, WpT, bp, nullptr, out, VOCAB, DMODEL);
    } else {
        ln_kernel<false><<<MROWS, 256, 0, stream>>>(x, fa, fb, hF);
        gemm_f32<<<dim3(VOCAB / FBN, MROWS / FBM), 256, 0, stream>>>(hF, Wp, bp, out, VOCAB, DMODEL);
    }
}